// Round 1
// baseline (336.800 us; speedup 1.0000x reference)
//
#include <hip/hip_runtime.h>
#include <hip/hip_bf16.h>

typedef short bf16x8 __attribute__((ext_vector_type(8)));
typedef float f32x4 __attribute__((ext_vector_type(4)));
typedef unsigned short u16x8 __attribute__((ext_vector_type(8)));
typedef unsigned short u16x4 __attribute__((ext_vector_type(4)));

#define D_DIM 512
#define C_CNT 4096
#define O_DIM 128
#define BM 64
#define CB 64
// exp(-0.35*d) = exp2(-0.35*log2(e)*d)
#define NB2 (-0.35f * 1.44269504088896340736f)

__device__ __forceinline__ unsigned short f2bf(float f) {
  union { float f; unsigned int u; } v; v.f = f;
  unsigned int u = v.u;
  return (unsigned short)((u + 0x7FFFu + ((u >> 16) & 1u)) >> 16);
}

__global__ __launch_bounds__(512)
void rbf_fused(const float* __restrict__ x, const float* __restrict__ cen,
               const float* __restrict__ W, const float* __restrict__ bias,
               float* __restrict__ out)
{
  // LDS: 64K + 16K + 16K + 8K + 0.5K = ~105 KB -> 1 block/CU
  __shared__ unsigned short xs[BM * D_DIM];     // x tile, bf16, swizzled
  __shared__ unsigned short cs[2][CB * 64];     // centers K-step, dbuf, swizzled
  __shared__ unsigned short Wt[O_DIM * CB];     // W chunk transposed [o][c], swizzled
  __shared__ unsigned short Pl[BM * CB];        // rbf tile [m][c], swizzled
  __shared__ float xsq[BM];
  __shared__ float csq[CB];

  const int tid  = threadIdx.x;
  const int lane = tid & 63;
  const int wv   = tid >> 6;        // 0..7
  const int mw   = wv >> 1;         // row-tile (16 rows) 0..3
  const int cw   = wv & 1;          // GEMM1 col half (32 centers)
  const int ow   = wv & 1;          // GEMM2 o half (64 outputs)
  const int l15  = lane & 15;
  const int lg   = lane >> 4;       // 0..3
  const int r0   = blockIdx.x * BM;

  // ---- stage x tile (fp32 -> bf16, swizzled) + row sums of squares ----
  {
    const int row = tid >> 3;       // 0..63
    const int qb  = tid & 7;        // float4 lane within row
    const float4* xr = (const float4*)(x + (size_t)(r0 + row) * D_DIM);
    float ss = 0.f;
#pragma unroll
    for (int i = 0; i < 16; ++i) {
      float4 v = xr[qb + 8 * i];
      ss += v.x * v.x + v.y * v.y + v.z * v.z + v.w * v.w;
      int k = (qb + 8 * i) * 4;
      int e = row * D_DIM + (k ^ ((row & 7) << 3));
      u16x4 h;
      h[0] = f2bf(v.x); h[1] = f2bf(v.y); h[2] = f2bf(v.z); h[3] = f2bf(v.w);
      *(u16x4*)&xs[e] = h;
    }
    ss += __shfl_xor(ss, 1);
    ss += __shfl_xor(ss, 2);
    ss += __shfl_xor(ss, 4);
    if ((tid & 7) == 0) xsq[row] = ss;
  }

  const f32x4 zero4 = {0.f, 0.f, 0.f, 0.f};
  f32x4 sacc[2] = {zero4, zero4};
  f32x4 oacc[4] = {zero4, zero4, zero4, zero4};

  __syncthreads();

  for (int cc = 0; cc < C_CNT / CB; ++cc) {
    const int c0 = cc * CB;

    // ---- stage W chunk transposed: Wt[o][c] bf16, swizzled ----
    {
      const int o  = tid & 127;
      const int ch = tid >> 7;      // 0..3 -> c range ch*16 .. ch*16+15
      const float* wp = W + (size_t)(c0 + ch * 16) * O_DIM + o;
      u16x8 p0, p1;
#pragma unroll
      for (int j = 0; j < 8; ++j) p0[j] = f2bf(wp[j * O_DIM]);
#pragma unroll
      for (int j = 0; j < 8; ++j) p1[j] = f2bf(wp[(8 + j) * O_DIM]);
      const int sw = (o & 7) << 3;
      *(u16x8*)&Wt[o * CB + ((ch * 16) ^ sw)]     = p0;
      *(u16x8*)&Wt[o * CB + ((ch * 16 + 8) ^ sw)] = p1;
    }

    // ---- K loop: S = X * Cen^T over D=512 in steps of 64 ----
    float cp0 = 0.f, cp1 = 0.f;
    for (int kk = 0; kk < 8; ++kk) {
      // stage centers K-step into cs[kk&1], accumulate c_sq partials in fp32
      {
        const int cr0 = tid >> 4;         // 0..31
        const int kc0 = tid & 15;         // float4 within the 64-wide K step
        const float4 v0 = *(const float4*)(cen + (size_t)(c0 + cr0) * D_DIM + kk * 64 + kc0 * 4);
        cp0 += v0.x * v0.x + v0.y * v0.y + v0.z * v0.z + v0.w * v0.w;
        u16x4 h0; h0[0] = f2bf(v0.x); h0[1] = f2bf(v0.y); h0[2] = f2bf(v0.z); h0[3] = f2bf(v0.w);
        *(u16x4*)&cs[kk & 1][cr0 * 64 + ((kc0 * 4) ^ ((cr0 & 7) << 3))] = h0;

        const int cr1 = cr0 + 32;
        const float4 v1 = *(const float4*)(cen + (size_t)(c0 + cr1) * D_DIM + kk * 64 + kc0 * 4);
        cp1 += v1.x * v1.x + v1.y * v1.y + v1.z * v1.z + v1.w * v1.w;
        u16x4 h1; h1[0] = f2bf(v1.x); h1[1] = f2bf(v1.y); h1[2] = f2bf(v1.z); h1[3] = f2bf(v1.w);
        *(u16x4*)&cs[kk & 1][cr1 * 64 + ((kc0 * 4) ^ ((cr1 & 7) << 3))] = h1;
      }
      __syncthreads();
      // MFMA: per wave 2 K-substeps x 2 col-tiles
#pragma unroll
      for (int ks = 0; ks < 2; ++ks) {
        const int arow = mw * 16 + l15;
        const int ak   = kk * 64 + ks * 32 + lg * 8;
        bf16x8 a = *(const bf16x8*)&xs[arow * D_DIM + (ak ^ ((arow & 7) << 3))];
#pragma unroll
        for (int ct = 0; ct < 2; ++ct) {
          const int crow = cw * 32 + ct * 16 + l15;
          const int bk   = ks * 32 + lg * 8;
          bf16x8 b = *(const bf16x8*)&cs[kk & 1][crow * 64 + (bk ^ ((crow & 7) << 3))];
          sacc[ct] = __builtin_amdgcn_mfma_f32_16x16x32_bf16(a, b, sacc[ct], 0, 0, 0);
        }
      }
    }

    // ---- c_sq: reduce over 16-lane groups, write to LDS ----
    cp0 += __shfl_xor(cp0, 1); cp0 += __shfl_xor(cp0, 2);
    cp0 += __shfl_xor(cp0, 4); cp0 += __shfl_xor(cp0, 8);
    cp1 += __shfl_xor(cp1, 1); cp1 += __shfl_xor(cp1, 2);
    cp1 += __shfl_xor(cp1, 4); cp1 += __shfl_xor(cp1, 8);
    if (l15 == 0) { csq[tid >> 4] = cp0; csq[(tid >> 4) + 32] = cp1; }
    __syncthreads();

    // ---- rbf = exp(-beta * (x2 + c2 - 2S)) -> Pl (bf16, swizzled) ----
#pragma unroll
    for (int ct = 0; ct < 2; ++ct) {
      const int cl = cw * 32 + ct * 16 + l15;
      const float cq = csq[cl];
#pragma unroll
      for (int r = 0; r < 4; ++r) {
        const int m = mw * 16 + lg * 4 + r;   // C/D layout: row=(lane>>4)*4+reg, col=lane&15
        const float val = exp2f(NB2 * (xsq[m] + cq - 2.f * sacc[ct][r]));
        Pl[m * 64 + (cl ^ ((m & 7) << 3))] = f2bf(val);
      }
      sacc[ct] = zero4;
    }
    __syncthreads();

    // ---- GEMM2: oacc += P * W_chunk ----
#pragma unroll
    for (int ks = 0; ks < 2; ++ks) {
      const int am = mw * 16 + l15;
      const int ak = ks * 32 + lg * 8;
      bf16x8 a = *(const bf16x8*)&Pl[am * 64 + (ak ^ ((am & 7) << 3))];
#pragma unroll
      for (int ot = 0; ot < 4; ++ot) {
        const int o = ow * 64 + ot * 16 + l15;
        bf16x8 b = *(const bf16x8*)&Wt[o * CB + (ak ^ ((o & 7) << 3))];
        oacc[ot] = __builtin_amdgcn_mfma_f32_16x16x32_bf16(a, b, oacc[ot], 0, 0, 0);
      }
    }
    __syncthreads();
  }

  // ---- epilogue: out = oacc + bias ----
#pragma unroll
  for (int ot = 0; ot < 4; ++ot) {
    const int o = ow * 64 + ot * 16 + l15;
    const float bb = bias[o];
#pragma unroll
    for (int r = 0; r < 4; ++r) {
      const int m = mw * 16 + lg * 4 + r;
      out[(size_t)(r0 + m) * O_DIM + o] = oacc[ot][r] + bb;
    }
  }
}

extern "C" void kernel_launch(void* const* d_in, const int* in_sizes, int n_in,
                              void* d_out, int out_size, void* d_ws, size_t ws_size,
                              hipStream_t stream) {
  (void)in_sizes; (void)n_in; (void)d_ws; (void)ws_size; (void)out_size;
  const float* x   = (const float*)d_in[0];
  const float* cen = (const float*)d_in[1];
  const float* W   = (const float*)d_in[2];
  const float* b   = (const float*)d_in[3];
  float* out = (float*)d_out;
  rbf_fused<<<dim3(16384 / BM), dim3(512), 0, stream>>>(x, cen, W, b, out);
}

// Round 2
// 164.590 us; speedup vs baseline: 2.0463x; 2.0463x over previous
//
#include <hip/hip_runtime.h>
#include <hip/hip_bf16.h>

typedef short bf16x8 __attribute__((ext_vector_type(8)));
typedef float f32x4 __attribute__((ext_vector_type(4)));
typedef unsigned short u16x4 __attribute__((ext_vector_type(4)));
typedef unsigned short u16;

#define NB2 (-0.35f * 1.44269504088896340736f)

__device__ __forceinline__ u16 f2bf(float f) {
  union { float f; unsigned int u; } v; v.f = f;
  unsigned int x = v.u;
  return (u16)((x + 0x7FFFu + ((x >> 16) & 1u)) >> 16);
}

#define GLOAD_LDS(g, l) __builtin_amdgcn_global_load_lds( \
    (const __attribute__((address_space(1))) unsigned int*)(g), \
    (__attribute__((address_space(3))) unsigned int*)(l), 16, 0, 0)

// ---------- preprocessing: centers -> bf16 + csq ----------
__global__ __launch_bounds__(128)
void prep_cen(const float* __restrict__ cen, u16* __restrict__ cbf,
              float* __restrict__ csq) {
  const int row = blockIdx.x, t = threadIdx.x;
  float4 v = ((const float4*)(cen + (size_t)row * 512))[t];
  u16x4 h; h[0] = f2bf(v.x); h[1] = f2bf(v.y); h[2] = f2bf(v.z); h[3] = f2bf(v.w);
  *(u16x4*)&cbf[(size_t)row * 512 + t * 4] = h;
  float ss = v.x * v.x + v.y * v.y + v.z * v.z + v.w * v.w;
  ss += __shfl_xor(ss, 1);  ss += __shfl_xor(ss, 2);
  ss += __shfl_xor(ss, 4);  ss += __shfl_xor(ss, 8);
  ss += __shfl_xor(ss, 16); ss += __shfl_xor(ss, 32);
  __shared__ float r2[2];
  if ((t & 63) == 0) r2[t >> 6] = ss;
  __syncthreads();
  if (t == 0) csq[row] = r2[0] + r2[1];
}

// ---------- preprocessing: W [4096][128] f32 -> Wt [128][4096] bf16 ----------
__global__ __launch_bounds__(256)
void prep_w(const float* __restrict__ W, u16* __restrict__ wt) {
  __shared__ u16 t_[128 * 66];
  const int c0 = blockIdx.x * 64;
  const int t = threadIdx.x;
#pragma unroll
  for (int it = 0; it < 32; ++it) {
    int idx = it * 256 + t;          // 0..8191
    int cl = idx >> 7;               // 0..63
    int o  = idx & 127;
    t_[o * 66 + cl] = f2bf(W[(size_t)(c0 + cl) * 128 + o]);
  }
  __syncthreads();
#pragma unroll
  for (int it = 0; it < 8; ++it) {
    int idx = it * 256 + t;          // 0..2047
    int o  = idx >> 4;               // 0..127
    int cq = idx & 15;
    u16x4 h;
    h[0] = t_[o * 66 + cq * 4 + 0]; h[1] = t_[o * 66 + cq * 4 + 1];
    h[2] = t_[o * 66 + cq * 4 + 2]; h[3] = t_[o * 66 + cq * 4 + 3];
    *(u16x4*)&wt[(size_t)o * 4096 + c0 + cq * 4] = h;
  }
}

// ---------- main fused kernel ----------
__global__ __launch_bounds__(512, 2)
void rbf_main(const float* __restrict__ x, const u16* __restrict__ cbf,
              const u16* __restrict__ wtg, const float* __restrict__ csq,
              const float* __restrict__ bias, float* __restrict__ out)
{
  __shared__ u16 cs[4][4096];   // centers K-step buffers (64 c x 64 k), 32 KB
  __shared__ u16 wt[2][8192];   // W chunk [128 o][64 c] dbuf, 32 KB
  __shared__ u16 pl[4096];      // P tile [64 m][64 c], 8 KB
  __shared__ float xsq_s[64];

  const int tid = threadIdx.x;
  const int lane = tid & 63;
  const int wv = tid >> 6;
  const int mw = wv >> 1;          // m-tile 0..3
  const int cw = wv & 1;           // center half / o half
  const int l15 = lane & 15;
  const int lg = lane >> 4;
  const size_t r0 = (size_t)blockIdx.x * 64;

  // staging per-thread offsets (pre-swizzled global source, linear LDS dest)
  const int scr = tid >> 3;        // row within staged tile
  const int sgk = tid & 7;         // 16B granule
  const int cen_off = scr * 512 + ((sgk ^ (scr & 7)) * 8);
  const int wt_off  = scr * 4096 + ((sgk ^ (scr & 7)) * 8);
  u16* const cs_dst = ((u16*)cs) + tid * 8;
  u16* const wt_dst = ((u16*)wt) + tid * 8;

#define STAGE_CS(ccn, kkn, slot) \
  GLOAD_LDS(cbf + (ccn) * 32768 + (kkn) * 64 + cen_off, cs_dst + (slot) * 4096)
#define STAGE_W(ccn, slot) do { \
  GLOAD_LDS(wtg + wt_off + (ccn) * 64,          wt_dst + (slot) * 8192);        \
  GLOAD_LDS(wtg + wt_off + 262144 + (ccn) * 64, wt_dst + (slot) * 8192 + 4096); \
} while (0)

  // prologue: stage cs(0), W(0), cs(1), cs(2)
  STAGE_CS(0, 0, 0);
  STAGE_W(0, 0);
  STAGE_CS(0, 1, 1);
  STAGE_CS(0, 2, 2);

  // ---- x fragments -> registers + row sums of squares ----
  bf16x8 xf[16];
  {
    const float* xr = x + (r0 + mw * 16 + l15) * 512 + lg * 8;
    float ss = 0.f;
#pragma unroll
    for (int g = 0; g < 4; ++g) {
#pragma unroll
      for (int q = 0; q < 4; ++q) {
        const int f = g * 4 + q;
        float4 a = *(const float4*)(xr + f * 32);
        float4 b = *(const float4*)(xr + f * 32 + 4);
        ss += a.x * a.x + a.y * a.y + a.z * a.z + a.w * a.w
            + b.x * b.x + b.y * b.y + b.z * b.z + b.w * b.w;
        bf16x8 h;
        h[0] = (short)f2bf(a.x); h[1] = (short)f2bf(a.y);
        h[2] = (short)f2bf(a.z); h[3] = (short)f2bf(a.w);
        h[4] = (short)f2bf(b.x); h[5] = (short)f2bf(b.y);
        h[6] = (short)f2bf(b.z); h[7] = (short)f2bf(b.w);
        xf[f] = h;
      }
      __builtin_amdgcn_sched_barrier(0);
    }
    ss += __shfl_xor(ss, 16);
    ss += __shfl_xor(ss, 32);
    if (lg == 0) xsq_s[mw * 16 + l15] = ss;
  }
  asm volatile("s_waitcnt lgkmcnt(0)" ::: "memory");
  __builtin_amdgcn_s_barrier();
  float xq[4];
#pragma unroll
  for (int r = 0; r < 4; ++r) xq[r] = xsq_s[mw * 16 + lg * 4 + r];

  float cq0 = csq[cw * 32 + l15];
  float cq1 = csq[cw * 32 + 16 + l15];

  // LDS read offsets (element units, swizzled)
  int bo[2][2], wo[2][4], po[2];
#pragma unroll
  for (int ks = 0; ks < 2; ++ks) {
    const int kb = ks * 32 + lg * 8;
#pragma unroll
    for (int ct = 0; ct < 2; ++ct) {
      const int cr = cw * 32 + ct * 16 + l15;
      bo[ks][ct] = cr * 64 + (kb ^ ((cr & 7) << 3));
    }
#pragma unroll
    for (int ot = 0; ot < 4; ++ot) {
      const int o = cw * 64 + ot * 16 + l15;
      wo[ks][ot] = o * 64 + (kb ^ ((o & 7) << 3));
    }
    const int am = mw * 16 + l15;
    po[ks] = am * 64 + (kb ^ ((am & 7) << 3));
  }

  const f32x4 z4 = {0.f, 0.f, 0.f, 0.f};
  f32x4 s0 = z4, s1 = z4;
  f32x4 oa[4] = {z4, z4, z4, z4};

#define KSTEP(cc, p, VM, DO_CS, DO_W) do { \
    asm volatile("s_waitcnt vmcnt(" #VM ")" ::: "memory"); \
    __builtin_amdgcn_s_barrier(); \
    __builtin_amdgcn_sched_barrier(0); \
    const u16* csb = &cs[(p) & 3][0]; \
    bf16x8 b00 = *(const bf16x8*)(csb + bo[0][0]); \
    bf16x8 b01 = *(const bf16x8*)(csb + bo[0][1]); \
    bf16x8 b10 = *(const bf16x8*)(csb + bo[1][0]); \
    bf16x8 b11 = *(const bf16x8*)(csb + bo[1][1]); \
    if (DO_CS) { STAGE_CS((cc) + (((p) + 3) >> 3), ((p) + 3) & 7, ((p) + 3) & 3); } \
    if (DO_W)  { STAGE_W((cc) + 1, ((cc) + 1) & 1); } \
    __builtin_amdgcn_s_setprio(1); \
    s0 = __builtin_amdgcn_mfma_f32_16x16x32_bf16(xf[2 * (p)],     b00, s0, 0, 0, 0); \
    s1 = __builtin_amdgcn_mfma_f32_16x16x32_bf16(xf[2 * (p)],     b01, s1, 0, 0, 0); \
    s0 = __builtin_amdgcn_mfma_f32_16x16x32_bf16(xf[2 * (p) + 1], b10, s0, 0, 0, 0); \
    s1 = __builtin_amdgcn_mfma_f32_16x16x32_bf16(xf[2 * (p) + 1], b11, s1, 0, 0, 0); \
    __builtin_amdgcn_s_setprio(0); \
  } while (0)

#define CHUNK_TAIL(cc) do { \
    const int c0l = cw * 32 + l15; \
    _Pragma("unroll") \
    for (int r = 0; r < 4; ++r) { \
      const int m = mw * 16 + lg * 4 + r; \
      const int sw = (m & 7) << 3; \
      float v0 = __builtin_amdgcn_exp2f(NB2 * (xq[r] + cq0 - 2.f * s0[r])); \
      float v1 = __builtin_amdgcn_exp2f(NB2 * (xq[r] + cq1 - 2.f * s1[r])); \
      pl[m * 64 + (c0l ^ sw)]        = f2bf(v0); \
      pl[m * 64 + ((c0l + 16) ^ sw)] = f2bf(v1); \
    } \
    s0 = z4; s1 = z4; \
    { const int nc = (cc) < 63 ? (cc) + 1 : 63; \
      cq0 = csq[nc * 64 + cw * 32 + l15]; \
      cq1 = csq[nc * 64 + cw * 32 + 16 + l15]; } \
    asm volatile("s_waitcnt lgkmcnt(0)" ::: "memory"); \
    __builtin_amdgcn_s_barrier(); \
    __builtin_amdgcn_sched_barrier(0); \
    const u16* wtb_ = &wt[(cc) & 1][0]; \
    _Pragma("unroll") \
    for (int ks = 0; ks < 2; ++ks) { \
      bf16x8 pa = *(const bf16x8*)(pl + po[ks]); \
      _Pragma("unroll") \
      for (int ot = 0; ot < 4; ++ot) { \
        bf16x8 wb = *(const bf16x8*)(wtb_ + wo[ks][ot]); \
        oa[ot] = __builtin_amdgcn_mfma_f32_16x16x32_bf16(pa, wb, oa[ot], 0, 0, 0); \
      } \
    } \
  } while (0)

  for (int cc = 0; cc < 63; ++cc) {
    KSTEP(cc, 0, 2, 1, 0);
    KSTEP(cc, 1, 2, 1, 0);
    KSTEP(cc, 2, 2, 1, 0);
    KSTEP(cc, 3, 2, 1, 0);
    KSTEP(cc, 4, 2, 1, 0);
    KSTEP(cc, 5, 2, 1, 1);
    KSTEP(cc, 6, 4, 1, 0);
    KSTEP(cc, 7, 4, 1, 0);
    CHUNK_TAIL(cc);
  }
  KSTEP(63, 0, 2, 1, 0);
  KSTEP(63, 1, 2, 1, 0);
  KSTEP(63, 2, 2, 1, 0);
  KSTEP(63, 3, 2, 1, 0);
  KSTEP(63, 4, 2, 1, 0);
  KSTEP(63, 5, 2, 0, 0);
  KSTEP(63, 6, 1, 0, 0);
  KSTEP(63, 7, 0, 0, 0);
  CHUNK_TAIL(63);

  // ---- epilogue: out = oa + bias ----
#pragma unroll
  for (int ot = 0; ot < 4; ++ot) {
    const int o = cw * 64 + ot * 16 + l15;
    const float bb = bias[o];
#pragma unroll
    for (int r = 0; r < 4; ++r) {
      const int m = mw * 16 + lg * 4 + r;
      out[(r0 + m) * 128 + o] = oa[ot][r] + bb;
    }
  }
#undef KSTEP
#undef CHUNK_TAIL
#undef STAGE_CS
#undef STAGE_W
}

extern "C" void kernel_launch(void* const* d_in, const int* in_sizes, int n_in,
                              void* d_out, int out_size, void* d_ws, size_t ws_size,
                              hipStream_t stream) {
  (void)in_sizes; (void)n_in; (void)out_size; (void)ws_size;
  const float* x   = (const float*)d_in[0];
  const float* cen = (const float*)d_in[1];
  const float* W   = (const float*)d_in[2];
  const float* b   = (const float*)d_in[3];
  u16* cbf  = (u16*)d_ws;                    // 4096*512 bf16 = 4 MB
  u16* wtg  = cbf + 4096 * 512;              // 128*4096 bf16 = 1 MB
  float* cs = (float*)(wtg + 128 * 4096);    // 4096 f32 = 16 KB
  prep_cen<<<4096, 128, 0, stream>>>(cen, cbf, cs);
  prep_w<<<64, 256, 0, stream>>>(W, wtg);
  rbf_main<<<256, 512, 0, stream>>>(x, cbf, wtg, cs, b, (float*)d_out);
}